// Round 2
// baseline (824.152 us; speedup 1.0000x reference)
//
#include <hip/hip_runtime.h>

#define NB 16
#define SEQ 4096
#define DIMC 1024
#define NH 16
#define DH 64
#define NC 32    // row chunks per batch
#define RPC 128  // rows per chunk

// ws layout (floats), all offsets %4==0 for float4 casts:
// q     : [16][1024]         off 0
// wtil  : [16][16][1024]     off 16384
// logits: [16][4096][16]     off 278528
// pmax  : [16][32][16]       off 1327104
// m     : [16][16]           off 1335296
// Lpart : [16][32][16]       off 1335552
// y     : [16][32][16][1024] off 1343744
// ho    : [16][1024]         off 9732352   (total 9748736 floats = 37.2 MB)

#define OFF_Q      0
#define OFF_WTIL   16384
#define OFF_LOGITS 278528
#define OFF_PMAX   1327104
#define OFF_M      1335296
#define OFF_LPART  1335552
#define OFF_Y      1343744
#define OFF_HO     9732352

// ---------- kq: q[b][j] = sum_c x[b,0,c] * Wq[c,j]
__global__ __launch_bounds__(256) void kq(const float* __restrict__ x,
                                          const float* __restrict__ Wq,
                                          float* __restrict__ qws) {
  const int jc = blockIdx.x, b = blockIdx.y, t = threadIdx.x;
  const int j = jc * 256 + t;
  const float* x0 = x + (size_t)b * SEQ * DIMC;
  float a = 0.f;
  #pragma unroll 8
  for (int c = 0; c < DIMC; ++c) a = fmaf(x0[c], Wq[(size_t)c * DIMC + j], a);
  qws[b * DIMC + j] = a;
}

// ---------- kw: wtil[b][h][c] = 0.125 * sum_d Wk[c, h*64+d] * q[b, h*64+d]
__global__ __launch_bounds__(256) void kw(const float* __restrict__ Wk,
                                          const float* __restrict__ qws,
                                          float* __restrict__ wtil) {
  const int h = blockIdx.x, b = blockIdx.y, t = threadIdx.x;
  const int v = t >> 6, dd = t & 63;
  const float qr = qws[b * DIMC + h * DH + dd];
  float* wt = wtil + ((size_t)b * NH + h) * DIMC;
  for (int c = v * 256; c < v * 256 + 256; ++c) {
    float p = Wk[(size_t)c * DIMC + h * DH + dd] * qr;
    #pragma unroll
    for (int o = 1; o < 64; o <<= 1) p += __shfl_xor(p, o);
    if (dd == 0) wt[c] = p * 0.125f;
  }
}

__device__ __forceinline__ float dot16(const float4* xv, const float4* wv) {
  float s = 0.f;
  #pragma unroll
  for (int i = 0; i < 4; ++i) {
    s = fmaf(xv[i].x, wv[i].x, s); s = fmaf(xv[i].y, wv[i].y, s);
    s = fmaf(xv[i].z, wv[i].z, s); s = fmaf(xv[i].w, wv[i].w, s);
  }
  return s;
}

// ---------- k_logit: logits[b][n][h], pmax[b][nc][h].  No LDS; wave w covers heads 4w..4w+3.
__global__ __launch_bounds__(256) void k_logit(const float* __restrict__ x,
                                               const float* __restrict__ wtil,
                                               float* __restrict__ logits,
                                               float* __restrict__ pmax) {
  const int nc = blockIdx.x, b = blockIdx.y, t = threadIdx.x;
  const int w = t >> 6, l = t & 63;
  const float4* wt4 = (const float4*)wtil + ((size_t)b * NH + w * 4) * 256;
  float4 wv[4][4];
  #pragma unroll
  for (int h = 0; h < 4; ++h)
    #pragma unroll
    for (int i = 0; i < 4; ++i) wv[h][i] = wt4[h * 256 + i * 64 + l];
  const float4* x4 = (const float4*)x + ((size_t)b * SEQ + nc * RPC) * 256;
  float* lg = logits + ((size_t)b * SEQ + (size_t)nc * RPC) * NH + w * 4;
  float4 vm = make_float4(-3.0e38f, -3.0e38f, -3.0e38f, -3.0e38f);

  for (int r = 0; r < RPC; ++r) {
    float4 xv[4];
    #pragma unroll
    for (int i = 0; i < 4; ++i) xv[i] = x4[r * 256 + i * 64 + l];
    float4 s;
    s.x = dot16(xv, wv[0]); s.y = dot16(xv, wv[1]);
    s.z = dot16(xv, wv[2]); s.w = dot16(xv, wv[3]);
    #pragma unroll
    for (int o = 1; o < 64; o <<= 1) {
      s.x += __shfl_xor(s.x, o); s.y += __shfl_xor(s.y, o);
      s.z += __shfl_xor(s.z, o); s.w += __shfl_xor(s.w, o);
    }
    vm.x = fmaxf(vm.x, s.x); vm.y = fmaxf(vm.y, s.y);
    vm.z = fmaxf(vm.z, s.z); vm.w = fmaxf(vm.w, s.w);
    if (l < 4) {
      float vsel = (l == 0) ? s.x : (l == 1) ? s.y : (l == 2) ? s.z : s.w;
      lg[r * NH + l] = vsel;
    }
    if ((r & 31) == 31) __syncthreads();  // bound wave drift for L2 x-reuse
  }
  if (l < 4) {
    float vsel = (l == 0) ? vm.x : (l == 1) ? vm.y : (l == 2) ? vm.z : vm.w;
    pmax[((size_t)b * NC + nc) * NH + w * 4 + l] = vsel;
  }
}

// ---------- k_m: m[b][h] = max over chunks
__global__ __launch_bounds__(256) void k_m(const float* __restrict__ pmax,
                                           float* __restrict__ m) {
  const int t = threadIdx.x;  // t = b*16+h
  const int b = t >> 4, h = t & 15;
  float v = -3.0e38f;
  #pragma unroll 8
  for (int nc = 0; nc < NC; ++nc) v = fmaxf(v, pmax[((size_t)b * NC + nc) * NH + h]);
  m[t] = v;
}

// ---------- k_acc: y[b][nc][h][c] = sum_{r in chunk} exp(logit - m) * x[r][c];  Lpart = sum exp
__global__ __launch_bounds__(256) void k_acc(const float* __restrict__ x,
                                             const float* __restrict__ logits,
                                             const float* __restrict__ m,
                                             float* __restrict__ y,
                                             float* __restrict__ Lpart) {
  const int nc = blockIdx.x, b = blockIdx.y, t = threadIdx.x;
  const float4* m4 = (const float4*)(m + b * 16);
  const float4 m0 = m4[0], m1 = m4[1], m2 = m4[2], m3 = m4[3];
  float4 acc[16];
  #pragma unroll
  for (int h = 0; h < 16; ++h) acc[h] = make_float4(0.f, 0.f, 0.f, 0.f);
  float4 L0 = make_float4(0, 0, 0, 0), L1 = L0, L2 = L0, L3 = L0;
  const float4* x4 = (const float4*)x + ((size_t)b * SEQ + nc * RPC) * 256;
  const float4* lg4 = (const float4*)(logits + ((size_t)b * SEQ + (size_t)nc * RPC) * NH);

  #pragma unroll 2
  for (int r = 0; r < RPC; ++r) {
    float4 g0 = lg4[r * 4 + 0], g1 = lg4[r * 4 + 1], g2 = lg4[r * 4 + 2], g3 = lg4[r * 4 + 3];
    float4 e0, e1, e2, e3;
    e0.x = __expf(g0.x - m0.x); e0.y = __expf(g0.y - m0.y); e0.z = __expf(g0.z - m0.z); e0.w = __expf(g0.w - m0.w);
    e1.x = __expf(g1.x - m1.x); e1.y = __expf(g1.y - m1.y); e1.z = __expf(g1.z - m1.z); e1.w = __expf(g1.w - m1.w);
    e2.x = __expf(g2.x - m2.x); e2.y = __expf(g2.y - m2.y); e2.z = __expf(g2.z - m2.z); e2.w = __expf(g2.w - m2.w);
    e3.x = __expf(g3.x - m3.x); e3.y = __expf(g3.y - m3.y); e3.z = __expf(g3.z - m3.z); e3.w = __expf(g3.w - m3.w);
    float4 xv = x4[r * 256 + t];
    #define ACC(h, ev) acc[h].x = fmaf(ev, xv.x, acc[h].x); acc[h].y = fmaf(ev, xv.y, acc[h].y); \
                       acc[h].z = fmaf(ev, xv.z, acc[h].z); acc[h].w = fmaf(ev, xv.w, acc[h].w)
    ACC(0, e0.x); ACC(1, e0.y); ACC(2, e0.z); ACC(3, e0.w);
    ACC(4, e1.x); ACC(5, e1.y); ACC(6, e1.z); ACC(7, e1.w);
    ACC(8, e2.x); ACC(9, e2.y); ACC(10, e2.z); ACC(11, e2.w);
    ACC(12, e3.x); ACC(13, e3.y); ACC(14, e3.z); ACC(15, e3.w);
    #undef ACC
    if (t < 64) {  // wave 0 tracks sum of e (uniform within wave)
      L0.x += e0.x; L0.y += e0.y; L0.z += e0.z; L0.w += e0.w;
      L1.x += e1.x; L1.y += e1.y; L1.z += e1.z; L1.w += e1.w;
      L2.x += e2.x; L2.y += e2.y; L2.z += e2.z; L2.w += e2.w;
      L3.x += e3.x; L3.y += e3.y; L3.z += e3.z; L3.w += e3.w;
    }
  }
  float4* y4 = (float4*)(y + (((size_t)b * NC + nc) * NH) * DIMC);
  #pragma unroll
  for (int h = 0; h < 16; ++h) y4[h * 256 + t] = acc[h];
  if (t == 0) {
    float* Lp = Lpart + ((size_t)b * NC + nc) * NH;
    Lp[0] = L0.x; Lp[1] = L0.y; Lp[2] = L0.z; Lp[3] = L0.w;
    Lp[4] = L1.x; Lp[5] = L1.y; Lp[6] = L1.z; Lp[7] = L1.w;
    Lp[8] = L2.x; Lp[9] = L2.y; Lp[10] = L2.z; Lp[11] = L2.w;
    Lp[12] = L3.x; Lp[13] = L3.y; Lp[14] = L3.z; Lp[15] = L3.w;
  }
}

// ---------- k_comb: ho[b, h*64+d] = (sum_s y[b,s,h,:] / L) . Wv[:, h*64+d]
__global__ __launch_bounds__(256) void k_comb(const float* __restrict__ y,
                                              const float* __restrict__ Lpart,
                                              const float* __restrict__ Wv,
                                              float* __restrict__ ho) {
  const int h = blockIdx.x, b = blockIdx.y, t = threadIdx.x;
  __shared__ float ylds[1024];
  __shared__ float red[256];
  __shared__ float sInvL;
  if (t < 32) {
    float lp = Lpart[((size_t)b * NC + t) * NH + h];
    #pragma unroll
    for (int o = 1; o < 32; o <<= 1) lp += __shfl_xor(lp, o);
    if (t == 0) sInvL = 1.f / lp;
  }
  __syncthreads();
  const float invL = sInvL;
  for (int c = t; c < DIMC; c += 256) {
    float a = 0.f;
    #pragma unroll
    for (int s = 0; s < NC; ++s)
      a += y[(((size_t)b * NC + s) * NH + h) * DIMC + c];
    ylds[c] = a * invL;
  }
  __syncthreads();
  const int d = t & 63, g = t >> 6;
  float part = 0.f;
  const float* wv = Wv + h * DH + d;
  #pragma unroll 4
  for (int c = g * 256; c < g * 256 + 256; ++c)
    part = fmaf(ylds[c], wv[(size_t)c * DIMC], part);
  red[t] = part;
  __syncthreads();
  if (t < 64)
    ho[(size_t)b * DIMC + h * DH + t] = red[t] + red[64 + t] + red[128 + t] + red[192 + t];
}

// ---------- k_out: out[b, jc*64+d] = ho[b,:] @ Wp[:, j] + bp[j]
__global__ __launch_bounds__(256) void k_out(const float* __restrict__ ho,
                                             const float* __restrict__ Wp,
                                             const float* __restrict__ bp,
                                             float* __restrict__ out) {
  const int jc = blockIdx.x, b = blockIdx.y, t = threadIdx.x;
  __shared__ float hs[1024];
  __shared__ float red[256];
  for (int i = t; i < 1024; i += 256) hs[i] = ho[(size_t)b * DIMC + i];
  __syncthreads();
  const int d = t & 63, g = t >> 6;
  const int j = jc * 64 + d;
  float a = 0.f;
  #pragma unroll 4
  for (int i = g * 256; i < g * 256 + 256; ++i)
    a = fmaf(hs[i], Wp[(size_t)i * DIMC + j], a);
  red[t] = a;
  __syncthreads();
  if (t < 64)
    out[(size_t)b * DIMC + jc * 64 + t] =
        red[t] + red[64 + t] + red[128 + t] + red[192 + t] + bp[jc * 64 + t];
}

extern "C" void kernel_launch(void* const* d_in, const int* in_sizes, int n_in,
                              void* d_out, int out_size, void* d_ws, size_t ws_size,
                              hipStream_t stream) {
  const float* x  = (const float*)d_in[0];
  const float* Wq = (const float*)d_in[1];
  const float* Wk = (const float*)d_in[2];
  const float* Wv = (const float*)d_in[3];
  const float* Wp = (const float*)d_in[4];
  const float* bp = (const float*)d_in[5];
  float* out = (float*)d_out;
  float* ws = (float*)d_ws;

  float* qws    = ws + OFF_Q;
  float* wtil   = ws + OFF_WTIL;
  float* logits = ws + OFF_LOGITS;
  float* pmax   = ws + OFF_PMAX;
  float* m      = ws + OFF_M;
  float* Lpart  = ws + OFF_LPART;
  float* y      = ws + OFF_Y;
  float* ho     = ws + OFF_HO;

  kq<<<dim3(4, NB), 256, 0, stream>>>(x, Wq, qws);
  kw<<<dim3(NH, NB), 256, 0, stream>>>(Wk, qws, wtil);
  k_logit<<<dim3(NC, NB), 256, 0, stream>>>(x, wtil, logits, pmax);
  k_m<<<1, 256, 0, stream>>>(pmax, m);
  k_acc<<<dim3(NC, NB), 256, 0, stream>>>(x, logits, m, y, Lpart);
  k_comb<<<dim3(NH, NB), 256, 0, stream>>>(y, Lpart, Wv, ho);
  k_out<<<dim3(NH, NB), 256, 0, stream>>>(ho, Wp, bp, out);
}

// Round 3
// 609.083 us; speedup vs baseline: 1.3531x; 1.3531x over previous
//
#include <hip/hip_runtime.h>

#define NB 16
#define SEQ 4096
#define DIMC 1024
#define NH 16
#define DH 64
#define NCL 128   // logit chunks per batch (32 rows each)
#define RPL 32    // rows per logit chunk

// ws layout (floats):
#define OFF_Q      0          // [16][1024]
#define OFF_WTIL   16384      // [16][16][1024]
#define OFF_LOGITS 278528     // [16][4096][16]  (h fastest)
#define OFF_P      1327104    // [16][4096][16]
#define OFF_PMAX   2375680    // [16][128][16]
#define OFF_M      2408448    // [16][16]
#define OFF_LPART  2408704    // [16][64][16]  (max ncAcc=64)
#define OFF_HO     2425088    // [16][1024]
#define OFF_Y      2441472    // [16][ncAcc][16][1024]
// ncAcc=64 -> 19218688 floats (76.9 MB); ncAcc=32 -> 10830080 floats (43.3 MB)

// ---------- kq: q[b][j] = x[b,0,:] . Wq[:,j]
__global__ __launch_bounds__(256) void kq(const float* __restrict__ x,
                                          const float* __restrict__ Wq,
                                          float* __restrict__ qws) {
  const int jc = blockIdx.x, b = blockIdx.y, t = threadIdx.x;
  const int d = t & 63, g = t >> 6;
  const int j = jc * 64 + d;
  const float* x0 = x + (size_t)b * SEQ * DIMC;
  __shared__ float red[256];
  float a = 0.f;
  #pragma unroll 8
  for (int c = g * 256; c < g * 256 + 256; ++c)
    a = fmaf(x0[c], Wq[(size_t)c * DIMC + j], a);
  red[t] = a;
  __syncthreads();
  if (t < 64)
    qws[b * DIMC + jc * 64 + t] = red[t] + red[64 + t] + red[128 + t] + red[192 + t];
}

// ---------- kw: wtil[b][h][c] = 0.125 * sum_d Wk[c, h*64+d] * q[b, h*64+d]
__global__ __launch_bounds__(256) void kw(const float* __restrict__ Wk,
                                          const float* __restrict__ qws,
                                          float* __restrict__ wtil) {
  const int cs = blockIdx.x, h = blockIdx.y, b = blockIdx.z, t = threadIdx.x;
  const int v = t >> 6, dd = t & 63;
  const float qd = qws[b * DIMC + h * DH + dd];
  float* wt = wtil + ((size_t)b * NH + h) * DIMC;
  const int c0 = cs * 256 + v * 64;
  for (int c = c0; c < c0 + 64; ++c) {
    float p = Wk[(size_t)c * DIMC + h * DH + dd] * qd;
    #pragma unroll
    for (int o = 1; o < 64; o <<= 1) p += __shfl_xor(p, o);
    if (dd == 0) wt[c] = p * 0.125f;
  }
}

__device__ __forceinline__ float dot16(const float4* xv, const float4* wv) {
  float s = 0.f;
  #pragma unroll
  for (int i = 0; i < 4; ++i) {
    s = fmaf(xv[i].x, wv[i].x, s); s = fmaf(xv[i].y, wv[i].y, s);
    s = fmaf(xv[i].z, wv[i].z, s); s = fmaf(xv[i].w, wv[i].w, s);
  }
  return s;
}

// ---------- k_logit: raw logits[b][n][h] + pmax per 32-row chunk. 2048 blocks.
__global__ __launch_bounds__(256) void k_logit(const float* __restrict__ x,
                                               const float* __restrict__ wtil,
                                               float* __restrict__ logits,
                                               float* __restrict__ pmax) {
  const int nc = blockIdx.x, b = blockIdx.y, t = threadIdx.x;
  const int w = t >> 6, l = t & 63;
  const float4* wt4 = (const float4*)wtil + ((size_t)b * NH + w * 4) * 256;
  float4 wv[4][4];
  #pragma unroll
  for (int h = 0; h < 4; ++h)
    #pragma unroll
    for (int i = 0; i < 4; ++i) wv[h][i] = wt4[h * 256 + i * 64 + l];
  const float4* x4 = (const float4*)x + ((size_t)b * SEQ + nc * RPL) * 256;
  float* lg = logits + ((size_t)b * SEQ + (size_t)nc * RPL) * NH + w * 4;
  float4 vm = make_float4(-3.0e38f, -3.0e38f, -3.0e38f, -3.0e38f);

  for (int r = 0; r < RPL; r += 2) {
    float4 xa[4], xb[4];
    #pragma unroll
    for (int i = 0; i < 4; ++i) xa[i] = x4[r * 256 + i * 64 + l];
    #pragma unroll
    for (int i = 0; i < 4; ++i) xb[i] = x4[(r + 1) * 256 + i * 64 + l];
    float4 sa, sb;
    sa.x = dot16(xa, wv[0]); sa.y = dot16(xa, wv[1]);
    sa.z = dot16(xa, wv[2]); sa.w = dot16(xa, wv[3]);
    sb.x = dot16(xb, wv[0]); sb.y = dot16(xb, wv[1]);
    sb.z = dot16(xb, wv[2]); sb.w = dot16(xb, wv[3]);
    #pragma unroll
    for (int o = 1; o < 64; o <<= 1) {
      sa.x += __shfl_xor(sa.x, o); sa.y += __shfl_xor(sa.y, o);
      sa.z += __shfl_xor(sa.z, o); sa.w += __shfl_xor(sa.w, o);
      sb.x += __shfl_xor(sb.x, o); sb.y += __shfl_xor(sb.y, o);
      sb.z += __shfl_xor(sb.z, o); sb.w += __shfl_xor(sb.w, o);
    }
    vm.x = fmaxf(vm.x, fmaxf(sa.x, sb.x)); vm.y = fmaxf(vm.y, fmaxf(sa.y, sb.y));
    vm.z = fmaxf(vm.z, fmaxf(sa.z, sb.z)); vm.w = fmaxf(vm.w, fmaxf(sa.w, sb.w));
    if (l < 4) {
      float va = (l == 0) ? sa.x : (l == 1) ? sa.y : (l == 2) ? sa.z : sa.w;
      float vb = (l == 0) ? sb.x : (l == 1) ? sb.y : (l == 2) ? sb.z : sb.w;
      lg[r * NH + l] = va;
      lg[(r + 1) * NH + l] = vb;
    }
  }
  if (l < 4) {
    float vsel = (l == 0) ? vm.x : (l == 1) ? vm.y : (l == 2) ? vm.z : vm.w;
    pmax[((size_t)b * NCL + nc) * NH + w * 4 + l] = vsel;
  }
}

// ---------- k_m: M[b][h] = global max over 128 chunk maxes; also zero ho
__global__ __launch_bounds__(256) void k_m(const float* __restrict__ pmax,
                                           float* __restrict__ m,
                                           float* __restrict__ ho) {
  const int t = threadIdx.x;  // t = b*16+h
  const int b = t >> 4, h = t & 15;
  float v = -3.0e38f;
  #pragma unroll 16
  for (int nc = 0; nc < NCL; ++nc) v = fmaxf(v, pmax[((size_t)b * NCL + nc) * NH + h]);
  m[t] = v;
  for (int i = t; i < NB * DIMC; i += 256) ho[i] = 0.f;
}

// ---------- k_p: p = exp(logit - M), elementwise over 1M floats
__global__ __launch_bounds__(256) void k_p(const float* __restrict__ logits,
                                           const float* __restrict__ m,
                                           float* __restrict__ p) {
  const int f4 = blockIdx.x * 256 + threadIdx.x;  // float4 index, 262144 total
  const int b = f4 >> 14;                          // 16384 float4 per batch
  const float4 m4 = ((const float4*)m)[b * 4 + (f4 & 3)];
  float4 g = ((const float4*)logits)[f4];
  float4 e;
  e.x = __expf(g.x - m4.x); e.y = __expf(g.y - m4.y);
  e.z = __expf(g.z - m4.z); e.w = __expf(g.w - m4.w);
  ((float4*)p)[f4] = e;
}

// ---------- k_acc: y[b][nc][h][c] = sum_{r in chunk} p[r][h] * x[r][c]; Lpart = sum p
__global__ __launch_bounds__(256) void k_acc(const float* __restrict__ x,
                                             const float* __restrict__ p,
                                             float* __restrict__ y,
                                             float* __restrict__ Lpart,
                                             int rpc) {
  const int nc = blockIdx.x, b = blockIdx.y, t = threadIdx.x;
  float4 acc[16];
  #pragma unroll
  for (int h = 0; h < 16; ++h) acc[h] = make_float4(0.f, 0.f, 0.f, 0.f);
  float4 L0 = make_float4(0, 0, 0, 0), L1 = L0, L2 = L0, L3 = L0;
  const float4* x4 = (const float4*)x + ((size_t)b * SEQ + (size_t)nc * rpc) * 256;
  const float4* p4 = (const float4*)(p + ((size_t)b * SEQ + (size_t)nc * rpc) * NH);

  for (int r = 0; r < rpc; r += 2) {
    float4 a0 = p4[r * 4 + 0], a1 = p4[r * 4 + 1], a2 = p4[r * 4 + 2], a3 = p4[r * 4 + 3];
    float4 b0 = p4[r * 4 + 4], b1 = p4[r * 4 + 5], b2 = p4[r * 4 + 6], b3 = p4[r * 4 + 7];
    float4 xva = x4[r * 256 + t];
    float4 xvb = x4[(r + 1) * 256 + t];
    #define ACC(h, ev, xv) acc[h].x = fmaf(ev, xv.x, acc[h].x); acc[h].y = fmaf(ev, xv.y, acc[h].y); \
                           acc[h].z = fmaf(ev, xv.z, acc[h].z); acc[h].w = fmaf(ev, xv.w, acc[h].w)
    ACC(0, a0.x, xva); ACC(1, a0.y, xva); ACC(2, a0.z, xva); ACC(3, a0.w, xva);
    ACC(4, a1.x, xva); ACC(5, a1.y, xva); ACC(6, a1.z, xva); ACC(7, a1.w, xva);
    ACC(8, a2.x, xva); ACC(9, a2.y, xva); ACC(10, a2.z, xva); ACC(11, a2.w, xva);
    ACC(12, a3.x, xva); ACC(13, a3.y, xva); ACC(14, a3.z, xva); ACC(15, a3.w, xva);
    ACC(0, b0.x, xvb); ACC(1, b0.y, xvb); ACC(2, b0.z, xvb); ACC(3, b0.w, xvb);
    ACC(4, b1.x, xvb); ACC(5, b1.y, xvb); ACC(6, b1.z, xvb); ACC(7, b1.w, xvb);
    ACC(8, b2.x, xvb); ACC(9, b2.y, xvb); ACC(10, b2.z, xvb); ACC(11, b2.w, xvb);
    ACC(12, b3.x, xvb); ACC(13, b3.y, xvb); ACC(14, b3.z, xvb); ACC(15, b3.w, xvb);
    #undef ACC
    if (t < 64) {
      L0.x += a0.x + b0.x; L0.y += a0.y + b0.y; L0.z += a0.z + b0.z; L0.w += a0.w + b0.w;
      L1.x += a1.x + b1.x; L1.y += a1.y + b1.y; L1.z += a1.z + b1.z; L1.w += a1.w + b1.w;
      L2.x += a2.x + b2.x; L2.y += a2.y + b2.y; L2.z += a2.z + b2.z; L2.w += a2.w + b2.w;
      L3.x += a3.x + b3.x; L3.y += a3.y + b3.y; L3.z += a3.z + b3.z; L3.w += a3.w + b3.w;
    }
  }
  float4* y4 = (float4*)y + (((size_t)b * gridDim.x + nc) * NH) * 256;
  #pragma unroll
  for (int h = 0; h < 16; ++h) y4[h * 256 + t] = acc[h];
  if (t == 0) {
    float* Lp = Lpart + ((size_t)b * gridDim.x + nc) * NH;
    Lp[0] = L0.x; Lp[1] = L0.y; Lp[2] = L0.z; Lp[3] = L0.w;
    Lp[4] = L1.x; Lp[5] = L1.y; Lp[6] = L1.z; Lp[7] = L1.w;
    Lp[8] = L2.x; Lp[9] = L2.y; Lp[10] = L2.z; Lp[11] = L2.w;
    Lp[12] = L3.x; Lp[13] = L3.y; Lp[14] = L3.z; Lp[15] = L3.w;
  }
}

// ---------- k_comb: ho[b, h*64+d] += (1/L) * sum_c ysum[c] * Wv[c, h*64+d], c-split by 4
__global__ __launch_bounds__(256) void k_comb(const float* __restrict__ y,
                                              const float* __restrict__ Lpart,
                                              const float* __restrict__ Wv,
                                              float* __restrict__ ho,
                                              int nch) {
  const int cs = blockIdx.x, h = blockIdx.y, b = blockIdx.z, t = threadIdx.x;
  __shared__ float ylds[256];
  __shared__ float red[256];
  __shared__ float sInvL;
  if (t < 64) {
    float lp = (t < nch) ? Lpart[((size_t)b * nch + t) * NH + h] : 0.f;
    #pragma unroll
    for (int o = 1; o < 64; o <<= 1) lp += __shfl_xor(lp, o);
    if (t == 0) sInvL = 1.f / lp;
  }
  const int c = cs * 256 + t;
  float ysum = 0.f;
  for (int s = 0; s < nch; ++s)
    ysum += y[(((size_t)b * nch + s) * NH + h) * DIMC + c];
  __syncthreads();
  ylds[t] = ysum * sInvL;
  __syncthreads();
  const int d = t & 63, g = t >> 6;
  float part = 0.f;
  #pragma unroll 4
  for (int k = 0; k < 64; ++k)
    part = fmaf(ylds[g * 64 + k], Wv[(size_t)(cs * 256 + g * 64 + k) * DIMC + h * DH + d], part);
  red[t] = part;
  __syncthreads();
  if (t < 64)
    atomicAdd(&ho[(size_t)b * DIMC + h * DH + t],
              red[t] + red[64 + t] + red[128 + t] + red[192 + t]);
}

// ---------- k_out: out[b, jc*64+d] = ho[b,:] . Wp[:, j] + bp[j]
__global__ __launch_bounds__(256) void k_out(const float* __restrict__ ho,
                                             const float* __restrict__ Wp,
                                             const float* __restrict__ bp,
                                             float* __restrict__ out) {
  const int jc = blockIdx.x, b = blockIdx.y, t = threadIdx.x;
  __shared__ float hs[1024];
  __shared__ float red[256];
  for (int i = t; i < 1024; i += 256) hs[i] = ho[(size_t)b * DIMC + i];
  __syncthreads();
  const int d = t & 63, g = t >> 6;
  const int j = jc * 64 + d;
  float a = 0.f;
  #pragma unroll 8
  for (int i = g * 256; i < g * 256 + 256; ++i)
    a = fmaf(hs[i], Wp[(size_t)i * DIMC + j], a);
  red[t] = a;
  __syncthreads();
  if (t < 64)
    out[(size_t)b * DIMC + jc * 64 + t] =
        red[t] + red[64 + t] + red[128 + t] + red[192 + t] + bp[jc * 64 + t];
}

extern "C" void kernel_launch(void* const* d_in, const int* in_sizes, int n_in,
                              void* d_out, int out_size, void* d_ws, size_t ws_size,
                              hipStream_t stream) {
  const float* x  = (const float*)d_in[0];
  const float* Wq = (const float*)d_in[1];
  const float* Wk = (const float*)d_in[2];
  const float* Wv = (const float*)d_in[3];
  const float* Wp = (const float*)d_in[4];
  const float* bp = (const float*)d_in[5];
  float* out = (float*)d_out;
  float* ws = (float*)d_ws;

  float* qws    = ws + OFF_Q;
  float* wtil   = ws + OFF_WTIL;
  float* logits = ws + OFF_LOGITS;
  float* p      = ws + OFF_P;
  float* pmax   = ws + OFF_PMAX;
  float* m      = ws + OFF_M;
  float* Lpart  = ws + OFF_LPART;
  float* ho     = ws + OFF_HO;
  float* y      = ws + OFF_Y;

  // choose accumulation chunking to fit workspace (same math either way)
  const int ncAcc = (ws_size >= (size_t)19218688 * 4) ? 64 : 32;
  const int rpc = SEQ / ncAcc;

  kq<<<dim3(16, NB), 256, 0, stream>>>(x, Wq, qws);
  kw<<<dim3(4, NH, NB), 256, 0, stream>>>(Wk, qws, wtil);
  k_logit<<<dim3(NCL, NB), 256, 0, stream>>>(x, wtil, logits, pmax);
  k_m<<<1, 256, 0, stream>>>(pmax, m, ho);
  k_p<<<1024, 256, 0, stream>>>(logits, m, p);
  k_acc<<<dim3(ncAcc, NB), 256, 0, stream>>>(x, p, y, Lpart, rpc);
  k_comb<<<dim3(4, NH, NB), 256, 0, stream>>>(y, Lpart, Wv, ho, ncAcc);
  k_out<<<dim3(16, NB), 256, 0, stream>>>(ho, Wp, bp, out);
}